// Round 8
// baseline (331.929 us; speedup 1.0000x reference)
//
#include <hip/hip_runtime.h>
#include <hip/hip_bf16.h>
#include <math.h>

#define Tt 4096
#define Dd 1024
#define Ff 2048
#define Ee 8

typedef unsigned short u16;
typedef short bf16x8 __attribute__((ext_vector_type(8)));
typedef float f32x4 __attribute__((ext_vector_type(4)));

__device__ __forceinline__ u16 f2bf(float f) {
  union { float f; unsigned u; } v; v.f = f;
  unsigned r = v.u + 0x7fffu + ((v.u >> 16) & 1u);
  return (u16)(r >> 16);
}

// async global->LDS, 16B per lane; LDS dest = wave-uniform base + lane*16
__device__ __forceinline__ void gload16(const void* g, void* l) {
  __builtin_amdgcn_global_load_lds(
      (const __attribute__((address_space(1))) unsigned int*)g,
      (__attribute__((address_space(3))) unsigned int*)l, 16, 0, 0);
}

// ---------------- Router (+ optional fused x->bf16). 4 tokens/block ----------------
__global__ __launch_bounds__(256) void router_kernel(
    const float* __restrict__ x, const float* __restrict__ gw,
    float* __restrict__ logits, u16* __restrict__ xb)
{
  int t = blockIdx.x * 4 + (threadIdx.x >> 6);
  int lane = threadIdx.x & 63;
  const float* xr = x + (size_t)t * Dd;
  float xv[16];
#pragma unroll
  for (int i = 0; i < 4; ++i) {
    float4 v = *reinterpret_cast<const float4*>(xr + lane * 16 + i * 4);
    xv[i*4+0] = v.x; xv[i*4+1] = v.y; xv[i*4+2] = v.z; xv[i*4+3] = v.w;
  }
  if (xb) {
#pragma unroll
    for (int i = 0; i < 4; ++i) {
      ushort4 b;
      b.x = f2bf(xv[i*4+0]); b.y = f2bf(xv[i*4+1]);
      b.z = f2bf(xv[i*4+2]); b.w = f2bf(xv[i*4+3]);
      *reinterpret_cast<ushort4*>(xb + (size_t)t * Dd + lane * 16 + i * 4) = b;
    }
  }
#pragma unroll
  for (int e = 0; e < Ee; ++e) {
    const float* gr = gw + (size_t)e * Dd + lane * 16;
    float s = 0.f;
#pragma unroll
    for (int i = 0; i < 4; ++i) {
      float4 g = *reinterpret_cast<const float4*>(gr + i * 4);
      s += xv[i*4+0]*g.x + xv[i*4+1]*g.y + xv[i*4+2]*g.z + xv[i*4+3]*g.w;
    }
#pragma unroll
    for (int o = 32; o > 0; o >>= 1) s += __shfl_xor(s, o);
    if (lane == 0) logits[(size_t)t * Ee + e] = s;
  }
}

// ---------------- build: single block, 8 per-expert groups ----------------
__global__ __launch_bounds__(256) void build_kernel(
    const float* __restrict__ logits, int* __restrict__ meta,
    int* __restrict__ list, float* __restrict__ wgt)
{
  __shared__ int hist[8], cur[8];
  const int tid = threadIdx.x;
  const int lane = tid & 63;
  if (tid < 8) hist[tid] = 0;
  __syncthreads();
  for (int it = 0; it < Tt / 256; ++it) {
    int t = it * 256 + tid;
    float4 lo = *reinterpret_cast<const float4*>(logits + (size_t)t * 8);
    float4 hi = *reinterpret_cast<const float4*>(logits + (size_t)t * 8 + 4);
    float s[8] = {lo.x, lo.y, lo.z, lo.w, hi.x, hi.y, hi.z, hi.w};
    int i1 = 0; float m1 = s[0];
#pragma unroll
    for (int e = 1; e < 8; ++e) if (s[e] > m1) { m1 = s[e]; i1 = e; }
    int i2 = -1; float m2 = -__builtin_inff();
#pragma unroll
    for (int e = 0; e < 8; ++e) if (e != i1 && s[e] > m2) { m2 = s[e]; i2 = e; }
#pragma unroll
    for (int k = 0; k < 2; ++k) {
      int gg = k ? i2 : i1;
      unsigned long long m = ~0ull;
#pragma unroll
      for (int b = 0; b < 3; ++b) {
        unsigned long long vb = __ballot((gg >> b) & 1);
        m &= ((gg >> b) & 1) ? vb : ~vb;
      }
      int rank = __popcll(m & ((1ull << lane) - 1));
      if (rank == 0) atomicAdd(&hist[gg], __popcll(m));
    }
  }
  __syncthreads();
  if (tid == 0) {
    int sacc = 0;
    for (int g = 0; g < 8; ++g) {
      meta[g] = hist[g];
      meta[32 + g] = sacc;
      cur[g] = sacc;
      sacc += hist[g];
    }
  }
  __syncthreads();
  for (int it = 0; it < Tt / 256; ++it) {
    int t = it * 256 + tid;
    float4 lo = *reinterpret_cast<const float4*>(logits + (size_t)t * 8);
    float4 hi = *reinterpret_cast<const float4*>(logits + (size_t)t * 8 + 4);
    float s[8] = {lo.x, lo.y, lo.z, lo.w, hi.x, hi.y, hi.z, hi.w};
    int i1 = 0; float m1 = s[0];
#pragma unroll
    for (int e = 1; e < 8; ++e) if (s[e] > m1) { m1 = s[e]; i1 = e; }
    int i2 = -1; float m2 = -__builtin_inff();
#pragma unroll
    for (int e = 0; e < 8; ++e) if (e != i1 && s[e] > m2) { m2 = s[e]; i2 = e; }
    float wa = 1.f / (1.f + expf(m2 - m1));   // renormalized top-2 softmax
#pragma unroll
    for (int k = 0; k < 2; ++k) {
      int gg = k ? i2 : i1;
      float w = k ? (1.f - wa) : wa;
      unsigned long long m = ~0ull;
#pragma unroll
      for (int b = 0; b < 3; ++b) {
        unsigned long long vb = __ballot((gg >> b) & 1);
        m &= ((gg >> b) & 1) ? vb : ~vb;
      }
      int rank = __popcll(m & ((1ull << lane) - 1));
      int ldr = __ffsll(m) - 1;
      int base = 0;
      if (rank == 0) base = atomicAdd(&cur[gg], __popcll(m));
      base = __shfl(base, ldr);
      list[base + rank] = t;
      wgt[base + rank] = w;
    }
  }
}

// transpose [R][C] f32 -> [C][R] bf16, per expert (blockIdx.z)
__global__ __launch_bounds__(256) void transpose_bf16_kernel(
    const float* __restrict__ in, u16* __restrict__ out, int R, int C)
{
  __shared__ u16 st[64][65];
  const size_t eoff = (size_t)blockIdx.z * R * C;
  const float* ip = in + eoff;
  u16* op = out + eoff;
  int r0 = blockIdx.y * 64, c0 = blockIdx.x * 64;
  int t = threadIdx.x;
  int rr = t >> 2;
  int cb = (t & 3) * 16;
#pragma unroll
  for (int i = 0; i < 4; ++i) {
    float4 v = *reinterpret_cast<const float4*>(ip + (size_t)(r0 + rr) * C + c0 + cb + i * 4);
    st[rr][cb + i*4 + 0] = f2bf(v.x);
    st[rr][cb + i*4 + 1] = f2bf(v.y);
    st[rr][cb + i*4 + 2] = f2bf(v.z);
    st[rr][cb + i*4 + 3] = f2bf(v.w);
  }
  __syncthreads();
#pragma unroll
  for (int i = 0; i < 4; ++i) {
    ushort4 b;
    b.x = st[cb + i*4 + 0][rr];
    b.y = st[cb + i*4 + 1][rr];
    b.z = st[cb + i*4 + 2][rr];
    b.w = st[cb + i*4 + 3][rr];
    *reinterpret_cast<ushort4*>(op + (size_t)(c0 + rr) * R + r0 + cb + i * 4) = b;
  }
}

// ---------------- grouped GEMM: 128x128, 4 waves, BK=64, k-major conflict-free LDS ----------------
// LDS chunk = 16 rows x 32 k, stored piece-major: lane (lp*16+lr) -> global
// row(lr), k-piece(lp); fragment reads are fully sequential 16B slots -> 0 conflicts
// (verified round 7). A/B tiles = 16 chunks each (8 row-chunks x 2 k-halves).
// MODE 0: h1[slot] = silu(xb[list[slot]] @ w1T[e]^T)
// MODE 1: out[list[slot]] += wgt[slot]*(h1[slot] @ w2T[e]^T)  (atomicAdd)
// Bbase layout: [e][n][k] bf16. One expert's plane per XCD (bijective swizzle).
template<int MODE, int N_, int K_>
__global__ __launch_bounds__(256) void gemm_g(
    const u16* __restrict__ Abase, const u16* __restrict__ Bbase,
    void* __restrict__ Cout, const int* __restrict__ meta,
    const int* __restrict__ list, const float* __restrict__ wgt)
{
  constexpr int NXc = N_ / 128;
  constexpr int NYc = 32;               // covers worst-case cnt=4096
  constexpr int CPX = NXc * NYc;
  constexpr int BUF = 128 * 64;         // u16 per tile buffer (16 KB)
  constexpr int NT  = K_ / 64;

  __shared__ u16 Al[2 * BUF];           // 64 KB total LDS
  __shared__ u16 Bl[2 * BUF];

  const int orig = blockIdx.x + NXc * (blockIdx.y + NYc * blockIdx.z);
  const int swz  = (orig & 7) * CPX + (orig >> 3);
  const int bz   = swz / (NXc * NYc);
  const int rem  = swz - bz * (NXc * NYc);
  const int by   = rem / NXc;
  const int bx   = rem - by * NXc;

  const int e   = bz;
  const int cnt = meta[e];
  if (by * 128 >= cnt) return;
  const int off = meta[32 + e];

  const int tid  = threadIdx.x;
  const int lane = tid & 63;
  const int wave = tid >> 6;
  const int wr   = wave >> 1, wc = wave & 1;
  const int n0   = bx * 128;
  const int lr   = lane & 15;           // row within 16-row chunk
  const int lp   = lane >> 4;           // k-piece (8 shorts)

  // staging: wave handles row-chunks rc = wave*2+{0,1}, k-halves {0,1}
  const u16* aptr[2];
  u16* alds[4];
#pragma unroll
  for (int c = 0; c < 2; ++c) {
    int rc = wave * 2 + c;
    int i = by * 128 + rc * 16 + lr;
    if (i >= cnt) i = cnt - 1;          // clamp tail (dup rows; epilogue guards)
    int srow = (MODE == 0) ? list[off + i] : (off + i);
    aptr[c] = Abase + (size_t)srow * K_ + lp * 8;
#pragma unroll
    for (int h = 0; h < 2; ++h)
      alds[c * 2 + h] = Al + (rc * 2 + h) * 512;
  }
  const u16* bptr[2];
  u16* blds[4];
#pragma unroll
  for (int c = 0; c < 2; ++c) {
    int rc = wave * 2 + c;
    bptr[c] = Bbase + ((size_t)e * N_ + n0 + rc * 16 + lr) * K_ + lp * 8;
#pragma unroll
    for (int h = 0; h < 2; ++h)
      blds[c * 2 + h] = Bl + (rc * 2 + h) * 512;
  }

  f32x4 acc[4][4] = {};

  // prologue: stage tile 0 into buffer 0 (8 glds per wave)
#pragma unroll
  for (int c = 0; c < 2; ++c)
#pragma unroll
    for (int h = 0; h < 2; ++h) {
      gload16(aptr[c] + h * 32, alds[c * 2 + h]);
      gload16(bptr[c] + h * 32, blds[c * 2 + h]);
    }
  __syncthreads();

  int cur = 0;
  for (int t = 0; t < NT; ++t) {
    if (t + 1 < NT) {                   // next tile flies under ds_read+MFMA
      int k0 = (t + 1) * 64;
      int nb = cur ^ 1;
#pragma unroll
      for (int c = 0; c < 2; ++c)
#pragma unroll
        for (int h = 0; h < 2; ++h) {
          gload16(aptr[c] + k0 + h * 32, alds[c * 2 + h] + nb * BUF);
          gload16(bptr[c] + k0 + h * 32, blds[c * 2 + h] + nb * BUF);
        }
    }
    const u16* Ab = Al + cur * BUF;
    const u16* Bb = Bl + cur * BUF;
#pragma unroll
    for (int h = 0; h < 2; ++h) {       // two 32-k halves per barrier
      bf16x8 af[4], bfv[4];
#pragma unroll
      for (int m = 0; m < 4; ++m)       // A row-chunk wr*4+m, k-half h
        af[m] = *reinterpret_cast<const bf16x8*>(
            &Ab[((wr*4 + m) * 2 + h) * 512 + lp * 128 + lr * 8]);
#pragma unroll
      for (int n = 0; n < 4; ++n)       // B row-chunk wc*4+n, k-half h
        bfv[n] = *reinterpret_cast<const bf16x8*>(
            &Bb[((wc*4 + n) * 2 + h) * 512 + lp * 128 + lr * 8]);
#pragma unroll
      for (int m = 0; m < 4; ++m)
#pragma unroll
        for (int n = 0; n < 4; ++n)
          acc[m][n] = __builtin_amdgcn_mfma_f32_16x16x32_bf16(af[m], bfv[n], acc[m][n], 0, 0, 0);
    }
    __syncthreads();                    // implicit vmcnt(0): next buffer ready
    cur ^= 1;
  }

  // epilogue: C/D frag layout col=lane&15, row=(lane>>4)*4+reg
  const int colb = n0 + wc * 64 + lr;
  const int rb4  = wr * 64 + lp * 4;
#pragma unroll
  for (int m = 0; m < 4; ++m) {
#pragma unroll
    for (int r = 0; r < 4; ++r) {
      int i = by * 128 + rb4 + m * 16 + r;
      if (i >= cnt) continue;
      if (MODE == 0) {
        u16* hp = (u16*)Cout + (size_t)(off + i) * N_;
#pragma unroll
        for (int n = 0; n < 4; ++n) {
          float v = acc[m][n][r];
          v = v / (1.f + expf(-v));            // silu
          hp[colb + n * 16] = f2bf(v);
        }
      } else {
        int   tok = list[off + i];
        float w   = wgt[off + i];
        float* o = (float*)Cout + (size_t)tok * N_;
#pragma unroll
        for (int n = 0; n < 4; ++n)
          atomicAdd(&o[colb + n * 16], w * acc[m][n][r]);
      }
    }
  }
}

// ---------------- dense fallback (small-ws path) ----------------
__global__ __launch_bounds__(256) void combine_kernel(
    const float* __restrict__ logits, float* __restrict__ combine)
{
  int t = blockIdx.x * 256 + threadIdx.x;
  if (t >= Tt) return;
  float4 lo = *reinterpret_cast<const float4*>(logits + (size_t)t * 8);
  float4 hi = *reinterpret_cast<const float4*>(logits + (size_t)t * 8 + 4);
  float s[8] = {lo.x, lo.y, lo.z, lo.w, hi.x, hi.y, hi.z, hi.w};
  int i1 = 0; float m1 = s[0];
#pragma unroll
  for (int e = 1; e < 8; ++e) if (s[e] > m1) { m1 = s[e]; i1 = e; }
  int i2 = -1; float m2 = -__builtin_inff();
#pragma unroll
  for (int e = 0; e < 8; ++e) if (e != i1 && s[e] > m2) { m2 = s[e]; i2 = e; }
  float wa = 1.f / (1.f + expf(m2 - m1));
#pragma unroll
  for (int e = 0; e < 8; ++e)
    combine[(size_t)t * 8 + e] = (e == i1) ? wa : ((e == i2) ? (1.f - wa) : 0.f);
}

template<int MODE, int N_, int K_>
__global__ __launch_bounds__(256) void gemm_dense(
    const float* __restrict__ A, const float* __restrict__ Bg,
    float* __restrict__ C, const float* __restrict__ combine,
    int expert, int first)
{
  constexpr int BM = 128, BN = 128, BK = 32, LDT = 40;
  __shared__ u16 Al[BM * LDT];
  __shared__ u16 Bl[BN * LDT];
  const int tid  = threadIdx.x;
  const int lane = tid & 63;
  const int wave = tid >> 6;
  const int wr = wave >> 1, wc = wave & 1;
  const int m0 = blockIdx.y * BM;
  const int n0 = blockIdx.x * BN;
  f32x4 acc[4][4] = {};
  for (int k0 = 0; k0 < K_; k0 += BK) {
#pragma unroll
    for (int i = 0; i < 4; ++i) {
      int f = tid + 256 * i;
      int row = f >> 3;
      int c4 = (f & 7) << 2;
      float4 v = *reinterpret_cast<const float4*>(A + (size_t)(m0 + row) * K_ + k0 + c4);
      ushort4 b;
      b.x = f2bf(v.x); b.y = f2bf(v.y); b.z = f2bf(v.z); b.w = f2bf(v.w);
      *reinterpret_cast<ushort4*>(&Al[row * LDT + c4]) = b;
    }
    {
      int n  = tid & 127;
      int kb = (tid >> 7) << 4;
      const float* bp = Bg + (size_t)(k0 + kb) * N_ + n0 + n;
      u16 tmp[16];
#pragma unroll
      for (int kk = 0; kk < 16; ++kk)
        tmp[kk] = f2bf(bp[(size_t)kk * N_]);
      u16* p = &Bl[n * LDT + kb];
#pragma unroll
      for (int i = 0; i < 4; ++i) {
        ushort4 b;
        b.x = tmp[i*4+0]; b.y = tmp[i*4+1]; b.z = tmp[i*4+2]; b.w = tmp[i*4+3];
        *reinterpret_cast<ushort4*>(p + i * 4) = b;
      }
    }
    __syncthreads();
    bf16x8 af[4], bfr[4];
    const int kq  = (lane >> 4) << 3;
    const int r16 = lane & 15;
#pragma unroll
    for (int m = 0; m < 4; ++m)
      af[m] = *reinterpret_cast<const bf16x8*>(&Al[(wr*64 + m*16 + r16) * LDT + kq]);
#pragma unroll
    for (int n = 0; n < 4; ++n)
      bfr[n] = *reinterpret_cast<const bf16x8*>(&Bl[(wc*64 + n*16 + r16) * LDT + kq]);
#pragma unroll
    for (int m = 0; m < 4; ++m)
#pragma unroll
      for (int n = 0; n < 4; ++n)
        acc[m][n] = __builtin_amdgcn_mfma_f32_16x16x32_bf16(af[m], bfr[n], acc[m][n], 0, 0, 0);
    __syncthreads();
  }
  const int col0 = n0 + wc * 64 + (lane & 15);
  const int rbs  = m0 + wr * 64 + ((lane >> 4) << 2);
#pragma unroll
  for (int m = 0; m < 4; ++m) {
#pragma unroll
    for (int r = 0; r < 4; ++r) {
      int row = rbs + m * 16 + r;
      if (MODE == 0) {
#pragma unroll
        for (int n = 0; n < 4; ++n) {
          float v = acc[m][n][r];
          v = v / (1.f + expf(-v));
          C[(size_t)row * N_ + col0 + n * 16] = v;
        }
      } else {
        float w = combine[(size_t)row * Ee + expert];
        if (first) {
#pragma unroll
          for (int n = 0; n < 4; ++n)
            C[(size_t)row * N_ + col0 + n * 16] = w * acc[m][n][r];
        } else {
#pragma unroll
          for (int n = 0; n < 4; ++n)
            C[(size_t)row * N_ + col0 + n * 16] += w * acc[m][n][r];
        }
      }
    }
  }
}

extern "C" void kernel_launch(void* const* d_in, const int* in_sizes, int n_in,
                              void* d_out, int out_size, void* d_ws, size_t ws_size,
                              hipStream_t stream)
{
  const float* x  = (const float*)d_in[0];   // [2,2048,1024]
  const float* gw = (const float*)d_in[1];   // [8,1024]
  const float* w1 = (const float*)d_in[2];   // [8,1024,2048]
  const float* w2 = (const float*)d_in[3];   // [8,2048,1024]
  float* out    = (float*)d_out;
  float* logits = out + (size_t)Tt * Dd;

  int*   meta = (int*)d_ws;                       // 64 ints
  int*   list = (int*)((char*)d_ws + 256);        // 8192 ints
  float* wgt  = (float*)((char*)d_ws + 256 + 32768);
  u16*   xb   = (u16*)((char*)d_ws + 262144);                         // 8 MB
  u16*   h1   = (u16*)((char*)d_ws + 262144 + 8388608);               // 32 MB
  u16*   wT   = (u16*)((char*)d_ws + 262144 + 8388608 + 33554432);    // 33.5 MB
  const size_t NEED = 262144ull + 8388608ull + 33554432ull + 33554432ull;

  if (ws_size >= NEED) {
    router_kernel<<<Tt / 4, 256, 0, stream>>>(x, gw, logits, xb);
    hipMemsetAsync(out, 0, (size_t)Tt * Dd * sizeof(float), stream);
    build_kernel<<<1, 256, 0, stream>>>(logits, meta, list, wgt);
    transpose_bf16_kernel<<<dim3(Ff/64, Dd/64, Ee), 256, 0, stream>>>(w1, wT, Dd, Ff);
    gemm_g<0, Ff, Dd><<<dim3(Ff/128, 32, 8), 256, 0, stream>>>(xb, wT, h1, meta, list, wgt);
    transpose_bf16_kernel<<<dim3(Dd/64, Ff/64, Ee), 256, 0, stream>>>(w2, wT, Ff, Dd);
    gemm_g<1, Dd, Ff><<<dim3(Dd/128, 32, 8), 256, 0, stream>>>(h1, wT, out, meta, list, wgt);
  } else {
    float* combine = (float*)d_ws;
    float* h1d     = combine + (size_t)Tt * Ee;
    router_kernel<<<Tt / 4, 256, 0, stream>>>(x, gw, logits, nullptr);
    combine_kernel<<<Tt / 256, 256, 0, stream>>>(logits, combine);
    size_t cb = (size_t)Tt * Ee * sizeof(float);
    size_t avail = ws_size > cb ? (ws_size - cb) : 0;
    long maxrows = (long)(avail / ((size_t)Ff * sizeof(float)));
    int chunk = (maxrows >= Tt) ? Tt : (int)((maxrows / 128) * 128);
    if (chunk < 128) chunk = 128;
    for (int c0 = 0; c0 < Tt; c0 += chunk) {
      int rows = (Tt - c0) < chunk ? (Tt - c0) : chunk;
      for (int e = 0; e < Ee; ++e) {
        gemm_dense<0, Ff, Dd><<<dim3(Ff/128, rows/128), 256, 0, stream>>>(
            x + (size_t)c0 * Dd, w1 + (size_t)e * Dd * Ff, h1d, nullptr, e, 0);
        gemm_dense<1, Dd, Ff><<<dim3(Dd/128, rows/128), 256, 0, stream>>>(
            h1d, w2 + (size_t)e * Ff * Dd, out + (size_t)c0 * Dd,
            combine + (size_t)c0 * Ee, e, (e == 0) ? 1 : 0);
      }
    }
  }
}

// Round 9
// 213.374 us; speedup vs baseline: 1.5556x; 1.5556x over previous
//
#include <hip/hip_runtime.h>
#include <hip/hip_bf16.h>
#include <math.h>

#define Tt 4096
#define Dd 1024
#define Ff 2048
#define Ee 8

typedef unsigned short u16;
typedef short bf16x8 __attribute__((ext_vector_type(8)));
typedef float f32x4 __attribute__((ext_vector_type(4)));

__device__ __forceinline__ u16 f2bf(float f) {
  union { float f; unsigned u; } v; v.f = f;
  unsigned r = v.u + 0x7fffu + ((v.u >> 16) & 1u);
  return (u16)(r >> 16);
}

// async global->LDS, 16B per lane; LDS dest = wave-uniform base + lane*16
__device__ __forceinline__ void gload16(const void* g, void* l) {
  __builtin_amdgcn_global_load_lds(
      (const __attribute__((address_space(1))) unsigned int*)g,
      (__attribute__((address_space(3))) unsigned int*)l, 16, 0, 0);
}

// ---------------- Router (+ optional fused x->bf16). 4 tokens/block ----------------
__global__ __launch_bounds__(256) void router_kernel(
    const float* __restrict__ x, const float* __restrict__ gw,
    float* __restrict__ logits, u16* __restrict__ xb)
{
  int t = blockIdx.x * 4 + (threadIdx.x >> 6);
  int lane = threadIdx.x & 63;
  const float* xr = x + (size_t)t * Dd;
  float xv[16];
#pragma unroll
  for (int i = 0; i < 4; ++i) {
    float4 v = *reinterpret_cast<const float4*>(xr + lane * 16 + i * 4);
    xv[i*4+0] = v.x; xv[i*4+1] = v.y; xv[i*4+2] = v.z; xv[i*4+3] = v.w;
  }
  if (xb) {
#pragma unroll
    for (int i = 0; i < 4; ++i) {
      ushort4 b;
      b.x = f2bf(xv[i*4+0]); b.y = f2bf(xv[i*4+1]);
      b.z = f2bf(xv[i*4+2]); b.w = f2bf(xv[i*4+3]);
      *reinterpret_cast<ushort4*>(xb + (size_t)t * Dd + lane * 16 + i * 4) = b;
    }
  }
#pragma unroll
  for (int e = 0; e < Ee; ++e) {
    const float* gr = gw + (size_t)e * Dd + lane * 16;
    float s = 0.f;
#pragma unroll
    for (int i = 0; i < 4; ++i) {
      float4 g = *reinterpret_cast<const float4*>(gr + i * 4);
      s += xv[i*4+0]*g.x + xv[i*4+1]*g.y + xv[i*4+2]*g.z + xv[i*4+3]*g.w;
    }
#pragma unroll
    for (int o = 32; o > 0; o >>= 1) s += __shfl_xor(s, o);
    if (lane == 0) logits[(size_t)t * Ee + e] = s;
  }
}

// ---------------- build: single block, 8 per-expert groups ----------------
__global__ __launch_bounds__(256) void build_kernel(
    const float* __restrict__ logits, int* __restrict__ meta,
    int* __restrict__ list, float* __restrict__ wgt)
{
  __shared__ int hist[8], cur[8];
  const int tid = threadIdx.x;
  const int lane = tid & 63;
  if (tid < 8) hist[tid] = 0;
  __syncthreads();
  for (int it = 0; it < Tt / 256; ++it) {
    int t = it * 256 + tid;
    float4 lo = *reinterpret_cast<const float4*>(logits + (size_t)t * 8);
    float4 hi = *reinterpret_cast<const float4*>(logits + (size_t)t * 8 + 4);
    float s[8] = {lo.x, lo.y, lo.z, lo.w, hi.x, hi.y, hi.z, hi.w};
    int i1 = 0; float m1 = s[0];
#pragma unroll
    for (int e = 1; e < 8; ++e) if (s[e] > m1) { m1 = s[e]; i1 = e; }
    int i2 = -1; float m2 = -__builtin_inff();
#pragma unroll
    for (int e = 0; e < 8; ++e) if (e != i1 && s[e] > m2) { m2 = s[e]; i2 = e; }
#pragma unroll
    for (int k = 0; k < 2; ++k) {
      int gg = k ? i2 : i1;
      unsigned long long m = ~0ull;
#pragma unroll
      for (int b = 0; b < 3; ++b) {
        unsigned long long vb = __ballot((gg >> b) & 1);
        m &= ((gg >> b) & 1) ? vb : ~vb;
      }
      int rank = __popcll(m & ((1ull << lane) - 1));
      if (rank == 0) atomicAdd(&hist[gg], __popcll(m));
    }
  }
  __syncthreads();
  if (tid == 0) {
    int sacc = 0;
    for (int g = 0; g < 8; ++g) {
      meta[g] = hist[g];
      meta[32 + g] = sacc;
      cur[g] = sacc;
      sacc += hist[g];
    }
  }
  __syncthreads();
  for (int it = 0; it < Tt / 256; ++it) {
    int t = it * 256 + tid;
    float4 lo = *reinterpret_cast<const float4*>(logits + (size_t)t * 8);
    float4 hi = *reinterpret_cast<const float4*>(logits + (size_t)t * 8 + 4);
    float s[8] = {lo.x, lo.y, lo.z, lo.w, hi.x, hi.y, hi.z, hi.w};
    int i1 = 0; float m1 = s[0];
#pragma unroll
    for (int e = 1; e < 8; ++e) if (s[e] > m1) { m1 = s[e]; i1 = e; }
    int i2 = -1; float m2 = -__builtin_inff();
#pragma unroll
    for (int e = 0; e < 8; ++e) if (e != i1 && s[e] > m2) { m2 = s[e]; i2 = e; }
    float wa = 1.f / (1.f + expf(m2 - m1));   // renormalized top-2 softmax
#pragma unroll
    for (int k = 0; k < 2; ++k) {
      int gg = k ? i2 : i1;
      float w = k ? (1.f - wa) : wa;
      unsigned long long m = ~0ull;
#pragma unroll
      for (int b = 0; b < 3; ++b) {
        unsigned long long vb = __ballot((gg >> b) & 1);
        m &= ((gg >> b) & 1) ? vb : ~vb;
      }
      int rank = __popcll(m & ((1ull << lane) - 1));
      int ldr = __ffsll(m) - 1;
      int base = 0;
      if (rank == 0) base = atomicAdd(&cur[gg], __popcll(m));
      base = __shfl(base, ldr);
      list[base + rank] = t;
      wgt[base + rank] = w;
    }
  }
}

// transpose [R][C] f32 -> [C][R] bf16, per expert (blockIdx.z)
__global__ __launch_bounds__(256) void transpose_bf16_kernel(
    const float* __restrict__ in, u16* __restrict__ out, int R, int C)
{
  __shared__ u16 st[64][65];
  const size_t eoff = (size_t)blockIdx.z * R * C;
  const float* ip = in + eoff;
  u16* op = out + eoff;
  int r0 = blockIdx.y * 64, c0 = blockIdx.x * 64;
  int t = threadIdx.x;
  int rr = t >> 2;
  int cb = (t & 3) * 16;
#pragma unroll
  for (int i = 0; i < 4; ++i) {
    float4 v = *reinterpret_cast<const float4*>(ip + (size_t)(r0 + rr) * C + c0 + cb + i * 4);
    st[rr][cb + i*4 + 0] = f2bf(v.x);
    st[rr][cb + i*4 + 1] = f2bf(v.y);
    st[rr][cb + i*4 + 2] = f2bf(v.z);
    st[rr][cb + i*4 + 3] = f2bf(v.w);
  }
  __syncthreads();
#pragma unroll
  for (int i = 0; i < 4; ++i) {
    ushort4 b;
    b.x = st[cb + i*4 + 0][rr];
    b.y = st[cb + i*4 + 1][rr];
    b.z = st[cb + i*4 + 2][rr];
    b.w = st[cb + i*4 + 3][rr];
    *reinterpret_cast<ushort4*>(op + (size_t)(c0 + rr) * R + r0 + cb + i * 4) = b;
  }
}

// ---------------- grouped GEMM: round-5 structure + piece-slot XOR swizzle ----------------
// LDS chunk = 16 rows x 4 k-pieces (16B each), linear row-major (glds dest).
// Swizzle: data piece p of row r lives in slot p ^ ((r>>1)&3). Staging lane
// loads piece (l&3)^((l>>3)&3) of its row (same 64B segment -> coalescing
// unchanged); fragment read uses slot q^((r>>1)&3) -> 16 lanes hit 8 banks,
// 2 each = conflict-free (m136: 2-way free). Both-sides-or-neither (T2 rule).
// MODE 0: h1[slot] = silu(xb[list[slot]] @ w1T[e]^T)
// MODE 1: out[list[slot]] += wgt[slot]*(h1[slot] @ w2T[e]^T)  (atomicAdd)
// Bbase layout: [e][n][k] bf16. One expert's plane per XCD (bijective swizzle).
template<int MODE, int N_, int K_>
__global__ __launch_bounds__(256) void gemm_g(
    const u16* __restrict__ Abase, const u16* __restrict__ Bbase,
    void* __restrict__ Cout, const int* __restrict__ meta,
    const int* __restrict__ list, const float* __restrict__ wgt)
{
  constexpr int NXc = N_ / 128;
  constexpr int NYc = 32;               // covers worst-case cnt=4096
  constexpr int CPX = NXc * NYc;
  constexpr int ABUF = 128 * 32, BBUF = 128 * 32;
  constexpr int NT  = K_ / 32;

  __shared__ u16 Al[2 * ABUF];
  __shared__ u16 Bl[2 * BBUF];

  const int orig = blockIdx.x + NXc * (blockIdx.y + NYc * blockIdx.z);
  const int swz  = (orig & 7) * CPX + (orig >> 3);
  const int bz   = swz / (NXc * NYc);
  const int rem  = swz - bz * (NXc * NYc);
  const int by   = rem / NXc;
  const int bx   = rem - by * NXc;

  const int e   = bz;
  const int cnt = meta[e];
  if (by * 128 >= cnt) return;
  const int off = meta[32 + e];

  const int tid  = threadIdx.x;
  const int lane = tid & 63;
  const int wave = tid >> 6;
  const int wr   = wave >> 1, wc = wave & 1;
  const int n0   = bx * 128;

  // staging: chunk = 16 rows; lane l -> row l>>2, swizzled k-piece
  const int l4 = lane >> 2;
  const int kp = (((lane & 3) ^ ((lane >> 3) & 3))) * 8;   // shorts

  const u16* aptr[2];
  u16* alds[2];
#pragma unroll
  for (int c = 0; c < 2; ++c) {
    int chunk = wave * 2 + c;
    int row = chunk * 16 + l4;
    int i = by * 128 + row;
    if (i >= cnt) i = cnt - 1;          // clamp tail (dup rows; epilogue guards)
    int srow = (MODE == 0) ? list[off + i] : (off + i);
    aptr[c] = Abase + (size_t)srow * K_ + kp;
    alds[c] = Al + chunk * 512;
  }
  const u16* bptr[2];
  u16* blds[2];
#pragma unroll
  for (int c = 0; c < 2; ++c) {
    int chunk = wave * 2 + c;
    int row = chunk * 16 + l4;
    bptr[c] = Bbase + ((size_t)e * N_ + n0 + row) * K_ + kp;
    blds[c] = Bl + chunk * 512;
  }

  f32x4 acc[4][4] = {};
  const int r16 = lane & 15;
  // swizzled read slot: q ^ ((r>>1)&3), in shorts
  const int kqs = (((lane >> 4) ^ ((lane >> 1) & 3))) * 8;

  // prologue: stage tile 0 into buffer 0
#pragma unroll
  for (int c = 0; c < 2; ++c) gload16(aptr[c], alds[c]);
#pragma unroll
  for (int c = 0; c < 2; ++c) gload16(bptr[c], blds[c]);
  __syncthreads();

  int cur = 0;
  for (int t = 0; t < NT; ++t) {
    if (t + 1 < NT) {                   // next tile flies under ds_read+MFMA
      int k0 = (t + 1) * 32;
      int nb = cur ^ 1;
#pragma unroll
      for (int c = 0; c < 2; ++c) gload16(aptr[c] + k0, alds[c] + nb * ABUF);
#pragma unroll
      for (int c = 0; c < 2; ++c) gload16(bptr[c] + k0, blds[c] + nb * BBUF);
    }
    const u16* Ab = Al + cur * ABUF;
    const u16* Bb = Bl + cur * BBUF;
    bf16x8 af[4], bfv[4];
#pragma unroll
    for (int m = 0; m < 4; ++m)
      af[m] = *reinterpret_cast<const bf16x8*>(&Ab[(wr*64 + m*16 + r16) * 32 + kqs]);
#pragma unroll
    for (int n = 0; n < 4; ++n)
      bfv[n] = *reinterpret_cast<const bf16x8*>(&Bb[(wc*64 + n*16 + r16) * 32 + kqs]);
#pragma unroll
    for (int m = 0; m < 4; ++m)
#pragma unroll
      for (int n = 0; n < 4; ++n)
        acc[m][n] = __builtin_amdgcn_mfma_f32_16x16x32_bf16(af[m], bfv[n], acc[m][n], 0, 0, 0);
    __syncthreads();                    // implicit vmcnt(0): next buffer ready
    cur ^= 1;
  }

  // epilogue: C/D frag layout col=lane&15, row=(lane>>4)*4+reg
  const int colb = n0 + wc * 64 + r16;
  const int rb4  = wr * 64 + ((lane >> 4) << 2);
#pragma unroll
  for (int m = 0; m < 4; ++m) {
#pragma unroll
    for (int r = 0; r < 4; ++r) {
      int i = by * 128 + rb4 + m * 16 + r;
      if (i >= cnt) continue;
      if (MODE == 0) {
        u16* hp = (u16*)Cout + (size_t)(off + i) * N_;
#pragma unroll
        for (int n = 0; n < 4; ++n) {
          float v = acc[m][n][r];
          v = v / (1.f + expf(-v));            // silu
          hp[colb + n * 16] = f2bf(v);
        }
      } else {
        int   tok = list[off + i];
        float w   = wgt[off + i];
        float* o = (float*)Cout + (size_t)tok * N_;
#pragma unroll
        for (int n = 0; n < 4; ++n)
          atomicAdd(&o[colb + n * 16], w * acc[m][n][r]);
      }
    }
  }
}

// ---------------- dense fallback (small-ws path) ----------------
__global__ __launch_bounds__(256) void combine_kernel(
    const float* __restrict__ logits, float* __restrict__ combine)
{
  int t = blockIdx.x * 256 + threadIdx.x;
  if (t >= Tt) return;
  float4 lo = *reinterpret_cast<const float4*>(logits + (size_t)t * 8);
  float4 hi = *reinterpret_cast<const float4*>(logits + (size_t)t * 8 + 4);
  float s[8] = {lo.x, lo.y, lo.z, lo.w, hi.x, hi.y, hi.z, hi.w};
  int i1 = 0; float m1 = s[0];
#pragma unroll
  for (int e = 1; e < 8; ++e) if (s[e] > m1) { m1 = s[e]; i1 = e; }
  int i2 = -1; float m2 = -__builtin_inff();
#pragma unroll
  for (int e = 0; e < 8; ++e) if (e != i1 && s[e] > m2) { m2 = s[e]; i2 = e; }
  float wa = 1.f / (1.f + expf(m2 - m1));
#pragma unroll
  for (int e = 0; e < 8; ++e)
    combine[(size_t)t * 8 + e] = (e == i1) ? wa : ((e == i2) ? (1.f - wa) : 0.f);
}

template<int MODE, int N_, int K_>
__global__ __launch_bounds__(256) void gemm_dense(
    const float* __restrict__ A, const float* __restrict__ Bg,
    float* __restrict__ C, const float* __restrict__ combine,
    int expert, int first)
{
  constexpr int BM = 128, BN = 128, BK = 32, LDT = 40;
  __shared__ u16 Al[BM * LDT];
  __shared__ u16 Bl[BN * LDT];
  const int tid  = threadIdx.x;
  const int lane = tid & 63;
  const int wave = tid >> 6;
  const int wr = wave >> 1, wc = wave & 1;
  const int m0 = blockIdx.y * BM;
  const int n0 = blockIdx.x * BN;
  f32x4 acc[4][4] = {};
  for (int k0 = 0; k0 < K_; k0 += BK) {
#pragma unroll
    for (int i = 0; i < 4; ++i) {
      int f = tid + 256 * i;
      int row = f >> 3;
      int c4 = (f & 7) << 2;
      float4 v = *reinterpret_cast<const float4*>(A + (size_t)(m0 + row) * K_ + k0 + c4);
      ushort4 b;
      b.x = f2bf(v.x); b.y = f2bf(v.y); b.z = f2bf(v.z); b.w = f2bf(v.w);
      *reinterpret_cast<ushort4*>(&Al[row * LDT + c4]) = b;
    }
    {
      int n  = tid & 127;
      int kb = (tid >> 7) << 4;
      const float* bp = Bg + (size_t)(k0 + kb) * N_ + n0 + n;
      u16 tmp[16];
#pragma unroll
      for (int kk = 0; kk < 16; ++kk)
        tmp[kk] = f2bf(bp[(size_t)kk * N_]);
      u16* p = &Bl[n * LDT + kb];
#pragma unroll
      for (int i = 0; i < 4; ++i) {
        ushort4 b;
        b.x = tmp[i*4+0]; b.y = tmp[i*4+1]; b.z = tmp[i*4+2]; b.w = tmp[i*4+3];
        *reinterpret_cast<ushort4*>(p + i * 4) = b;
      }
    }
    __syncthreads();
    bf16x8 af[4], bfr[4];
    const int kq  = (lane >> 4) << 3;
    const int r16 = lane & 15;
#pragma unroll
    for (int m = 0; m < 4; ++m)
      af[m] = *reinterpret_cast<const bf16x8*>(&Al[(wr*64 + m*16 + r16) * LDT + kq]);
#pragma unroll
    for (int n = 0; n < 4; ++n)
      bfr[n] = *reinterpret_cast<const bf16x8*>(&Bl[(wc*64 + n*16 + r16) * LDT + kq]);
#pragma unroll
    for (int m = 0; m < 4; ++m)
#pragma unroll
      for (int n = 0; n < 4; ++n)
        acc[m][n] = __builtin_amdgcn_mfma_f32_16x16x32_bf16(af[m], bfr[n], acc[m][n], 0, 0, 0);
    __syncthreads();
  }
  const int col0 = n0 + wc * 64 + (lane & 15);
  const int rbs  = m0 + wr * 64 + ((lane >> 4) << 2);
#pragma unroll
  for (int m = 0; m < 4; ++m) {
#pragma unroll
    for (int r = 0; r < 4; ++r) {
      int row = rbs + m * 16 + r;
      if (MODE == 0) {
#pragma unroll
        for (int n = 0; n < 4; ++n) {
          float v = acc[m][n][r];
          v = v / (1.f + expf(-v));
          C[(size_t)row * N_ + col0 + n * 16] = v;
        }
      } else {
        float w = combine[(size_t)row * Ee + expert];
        if (first) {
#pragma unroll
          for (int n = 0; n < 4; ++n)
            C[(size_t)row * N_ + col0 + n * 16] = w * acc[m][n][r];
        } else {
#pragma unroll
          for (int n = 0; n < 4; ++n)
            C[(size_t)row * N_ + col0 + n * 16] += w * acc[m][n][r];
        }
      }
    }
  }
}

extern "C" void kernel_launch(void* const* d_in, const int* in_sizes, int n_in,
                              void* d_out, int out_size, void* d_ws, size_t ws_size,
                              hipStream_t stream)
{
  const float* x  = (const float*)d_in[0];   // [2,2048,1024]
  const float* gw = (const float*)d_in[1];   // [8,1024]
  const float* w1 = (const float*)d_in[2];   // [8,1024,2048]
  const float* w2 = (const float*)d_in[3];   // [8,2048,1024]
  float* out    = (float*)d_out;
  float* logits = out + (size_t)Tt * Dd;

  int*   meta = (int*)d_ws;                       // 64 ints
  int*   list = (int*)((char*)d_ws + 256);        // 8192 ints
  float* wgt  = (float*)((char*)d_ws + 256 + 32768);
  u16*   xb   = (u16*)((char*)d_ws + 262144);                         // 8 MB
  u16*   h1   = (u16*)((char*)d_ws + 262144 + 8388608);               // 32 MB
  u16*   wT   = (u16*)((char*)d_ws + 262144 + 8388608 + 33554432);    // 33.5 MB
  const size_t NEED = 262144ull + 8388608ull + 33554432ull + 33554432ull;

  if (ws_size >= NEED) {
    router_kernel<<<Tt / 4, 256, 0, stream>>>(x, gw, logits, xb);
    hipMemsetAsync(out, 0, (size_t)Tt * Dd * sizeof(float), stream);
    build_kernel<<<1, 256, 0, stream>>>(logits, meta, list, wgt);
    transpose_bf16_kernel<<<dim3(Ff/64, Dd/64, Ee), 256, 0, stream>>>(w1, wT, Dd, Ff);
    gemm_g<0, Ff, Dd><<<dim3(Ff/128, 32, 8), 256, 0, stream>>>(xb, wT, h1, meta, list, wgt);
    transpose_bf16_kernel<<<dim3(Dd/64, Ff/64, Ee), 256, 0, stream>>>(w2, wT, Ff, Dd);
    gemm_g<1, Dd, Ff><<<dim3(Dd/128, 32, 8), 256, 0, stream>>>(h1, wT, out, meta, list, wgt);
  } else {
    float* combine = (float*)d_ws;
    float* h1d     = combine + (size_t)Tt * Ee;
    router_kernel<<<Tt / 4, 256, 0, stream>>>(x, gw, logits, nullptr);
    combine_kernel<<<Tt / 256, 256, 0, stream>>>(logits, combine);
    size_t cb = (size_t)Tt * Ee * sizeof(float);
    size_t avail = ws_size > cb ? (ws_size - cb) : 0;
    long maxrows = (long)(avail / ((size_t)Ff * sizeof(float)));
    int chunk = (maxrows >= Tt) ? Tt : (int)((maxrows / 128) * 128);
    if (chunk < 128) chunk = 128;
    for (int c0 = 0; c0 < Tt; c0 += chunk) {
      int rows = (Tt - c0) < chunk ? (Tt - c0) : chunk;
      for (int e = 0; e < Ee; ++e) {
        gemm_dense<0, Ff, Dd><<<dim3(Ff/128, rows/128), 256, 0, stream>>>(
            x + (size_t)c0 * Dd, w1 + (size_t)e * Dd * Ff, h1d, nullptr, e, 0);
        gemm_dense<1, Dd, Ff><<<dim3(Dd/128, rows/128), 256, 0, stream>>>(
            h1d, w2 + (size_t)e * Ff * Dd, out + (size_t)c0 * Dd,
            combine + (size_t)c0 * Ee, e, (e == 0) ? 1 : 0);
      }
    }
  }
}

// Round 10
// 207.249 us; speedup vs baseline: 1.6016x; 1.0296x over previous
//
#include <hip/hip_runtime.h>
#include <hip/hip_bf16.h>
#include <math.h>

#define Tt 4096
#define Dd 1024
#define Ff 2048
#define Ee 8

typedef unsigned short u16;
typedef short bf16x8 __attribute__((ext_vector_type(8)));
typedef float f32x4 __attribute__((ext_vector_type(4)));

__device__ __forceinline__ u16 f2bf(float f) {
  union { float f; unsigned u; } v; v.f = f;
  unsigned r = v.u + 0x7fffu + ((v.u >> 16) & 1u);
  return (u16)(r >> 16);
}

// async global->LDS, 16B per lane; LDS dest = wave-uniform base + lane*16
__device__ __forceinline__ void gload16(const void* g, void* l) {
  __builtin_amdgcn_global_load_lds(
      (const __attribute__((address_space(1))) unsigned int*)g,
      (__attribute__((address_space(3))) unsigned int*)l, 16, 0, 0);
}

// ---------------- Router (+ optional fused x->bf16). 4 tokens/block ----------------
__global__ __launch_bounds__(256) void router_kernel(
    const float* __restrict__ x, const float* __restrict__ gw,
    float* __restrict__ logits, u16* __restrict__ xb)
{
  int t = blockIdx.x * 4 + (threadIdx.x >> 6);
  int lane = threadIdx.x & 63;
  const float* xr = x + (size_t)t * Dd;
  float xv[16];
#pragma unroll
  for (int i = 0; i < 4; ++i) {
    float4 v = *reinterpret_cast<const float4*>(xr + lane * 16 + i * 4);
    xv[i*4+0] = v.x; xv[i*4+1] = v.y; xv[i*4+2] = v.z; xv[i*4+3] = v.w;
  }
  if (xb) {
#pragma unroll
    for (int i = 0; i < 4; ++i) {
      ushort4 b;
      b.x = f2bf(xv[i*4+0]); b.y = f2bf(xv[i*4+1]);
      b.z = f2bf(xv[i*4+2]); b.w = f2bf(xv[i*4+3]);
      *reinterpret_cast<ushort4*>(xb + (size_t)t * Dd + lane * 16 + i * 4) = b;
    }
  }
#pragma unroll
  for (int e = 0; e < Ee; ++e) {
    const float* gr = gw + (size_t)e * Dd + lane * 16;
    float s = 0.f;
#pragma unroll
    for (int i = 0; i < 4; ++i) {
      float4 g = *reinterpret_cast<const float4*>(gr + i * 4);
      s += xv[i*4+0]*g.x + xv[i*4+1]*g.y + xv[i*4+2]*g.z + xv[i*4+3]*g.w;
    }
#pragma unroll
    for (int o = 32; o > 0; o >>= 1) s += __shfl_xor(s, o);
    if (lane == 0) logits[(size_t)t * Ee + e] = s;
  }
}

// ---------------- build: single block, 8 per-expert groups ----------------
__global__ __launch_bounds__(256) void build_kernel(
    const float* __restrict__ logits, int* __restrict__ meta,
    int* __restrict__ list, float* __restrict__ wgt)
{
  __shared__ int hist[8], cur[8];
  const int tid = threadIdx.x;
  const int lane = tid & 63;
  if (tid < 8) hist[tid] = 0;
  __syncthreads();
  for (int it = 0; it < Tt / 256; ++it) {
    int t = it * 256 + tid;
    float4 lo = *reinterpret_cast<const float4*>(logits + (size_t)t * 8);
    float4 hi = *reinterpret_cast<const float4*>(logits + (size_t)t * 8 + 4);
    float s[8] = {lo.x, lo.y, lo.z, lo.w, hi.x, hi.y, hi.z, hi.w};
    int i1 = 0; float m1 = s[0];
#pragma unroll
    for (int e = 1; e < 8; ++e) if (s[e] > m1) { m1 = s[e]; i1 = e; }
    int i2 = -1; float m2 = -__builtin_inff();
#pragma unroll
    for (int e = 0; e < 8; ++e) if (e != i1 && s[e] > m2) { m2 = s[e]; i2 = e; }
#pragma unroll
    for (int k = 0; k < 2; ++k) {
      int gg = k ? i2 : i1;
      unsigned long long m = ~0ull;
#pragma unroll
      for (int b = 0; b < 3; ++b) {
        unsigned long long vb = __ballot((gg >> b) & 1);
        m &= ((gg >> b) & 1) ? vb : ~vb;
      }
      int rank = __popcll(m & ((1ull << lane) - 1));
      if (rank == 0) atomicAdd(&hist[gg], __popcll(m));
    }
  }
  __syncthreads();
  if (tid == 0) {
    int sacc = 0;
    for (int g = 0; g < 8; ++g) {
      meta[g] = hist[g];
      meta[32 + g] = sacc;
      cur[g] = sacc;
      sacc += hist[g];
    }
  }
  __syncthreads();
  for (int it = 0; it < Tt / 256; ++it) {
    int t = it * 256 + tid;
    float4 lo = *reinterpret_cast<const float4*>(logits + (size_t)t * 8);
    float4 hi = *reinterpret_cast<const float4*>(logits + (size_t)t * 8 + 4);
    float s[8] = {lo.x, lo.y, lo.z, lo.w, hi.x, hi.y, hi.z, hi.w};
    int i1 = 0; float m1 = s[0];
#pragma unroll
    for (int e = 1; e < 8; ++e) if (s[e] > m1) { m1 = s[e]; i1 = e; }
    int i2 = -1; float m2 = -__builtin_inff();
#pragma unroll
    for (int e = 0; e < 8; ++e) if (e != i1 && s[e] > m2) { m2 = s[e]; i2 = e; }
    float wa = 1.f / (1.f + expf(m2 - m1));   // renormalized top-2 softmax
#pragma unroll
    for (int k = 0; k < 2; ++k) {
      int gg = k ? i2 : i1;
      float w = k ? (1.f - wa) : wa;
      unsigned long long m = ~0ull;
#pragma unroll
      for (int b = 0; b < 3; ++b) {
        unsigned long long vb = __ballot((gg >> b) & 1);
        m &= ((gg >> b) & 1) ? vb : ~vb;
      }
      int rank = __popcll(m & ((1ull << lane) - 1));
      int ldr = __ffsll(m) - 1;
      int base = 0;
      if (rank == 0) base = atomicAdd(&cur[gg], __popcll(m));
      base = __shfl(base, ldr);
      list[base + rank] = t;
      wgt[base + rank] = w;
    }
  }
}

// transpose [R][C] f32 -> [C][R] bf16, per expert (blockIdx.z)
__global__ __launch_bounds__(256) void transpose_bf16_kernel(
    const float* __restrict__ in, u16* __restrict__ out, int R, int C)
{
  __shared__ u16 st[64][65];
  const size_t eoff = (size_t)blockIdx.z * R * C;
  const float* ip = in + eoff;
  u16* op = out + eoff;
  int r0 = blockIdx.y * 64, c0 = blockIdx.x * 64;
  int t = threadIdx.x;
  int rr = t >> 2;
  int cb = (t & 3) * 16;
#pragma unroll
  for (int i = 0; i < 4; ++i) {
    float4 v = *reinterpret_cast<const float4*>(ip + (size_t)(r0 + rr) * C + c0 + cb + i * 4);
    st[rr][cb + i*4 + 0] = f2bf(v.x);
    st[rr][cb + i*4 + 1] = f2bf(v.y);
    st[rr][cb + i*4 + 2] = f2bf(v.z);
    st[rr][cb + i*4 + 3] = f2bf(v.w);
  }
  __syncthreads();
#pragma unroll
  for (int i = 0; i < 4; ++i) {
    ushort4 b;
    b.x = st[cb + i*4 + 0][rr];
    b.y = st[cb + i*4 + 1][rr];
    b.z = st[cb + i*4 + 2][rr];
    b.w = st[cb + i*4 + 3][rr];
    *reinterpret_cast<ushort4*>(op + (size_t)(c0 + rr) * R + r0 + cb + i * 4) = b;
  }
}

// ---------------- grouped GEMM: r9 geometry + 3-buffer counted-vmcnt pipeline ----------------
// Geometry/staging/swizzle identical to r9 (coalesced source, 0 bank conflicts).
// Sync: ONE s_barrier per K-step; per-wave s_waitcnt vmcnt(4) (never 0 mid-loop);
// glds for tile t+2 issued into a third buffer while tile t is consumed ->
// each load has ~2 full K-steps to land. The vmcnt asm ("memory") is the
// per-iter compiler fence (no instruction pinning). T5 setprio around MFMA.
// Hazards: (a) per-wave vmcnt(4)+barrier => all waves' tile-t loads visible;
// (b) buf[t+2] writes vs buf[t] reads are disjoint; old readers of that buffer
// finished before the PREVIOUS barrier (reads precede barrier in program order,
// fenced by the vmcnt asm).
// MODE 0: h1[slot] = silu(xb[list[slot]] @ w1T[e]^T)
// MODE 1: out[list[slot]] += wgt[slot]*(h1[slot] @ w2T[e]^T)  (atomicAdd)
// Bbase layout: [e][n][k] bf16. One expert's plane per XCD (bijective swizzle).
template<int MODE, int N_, int K_>
__global__ __launch_bounds__(256) void gemm_g(
    const u16* __restrict__ Abase, const u16* __restrict__ Bbase,
    void* __restrict__ Cout, const int* __restrict__ meta,
    const int* __restrict__ list, const float* __restrict__ wgt)
{
  constexpr int NXc = N_ / 128;
  constexpr int NYc = 32;               // covers worst-case cnt=4096
  constexpr int CPX = NXc * NYc;
  constexpr int ABUF = 128 * 32;        // u16 per buffer (8 KB)
  constexpr int NT  = K_ / 32;

  __shared__ u16 Al[3 * ABUF];          // 3-deep rotation, 48 KB total
  __shared__ u16 Bl[3 * ABUF];

  const int orig = blockIdx.x + NXc * (blockIdx.y + NYc * blockIdx.z);
  const int swz  = (orig & 7) * CPX + (orig >> 3);
  const int bz   = swz / (NXc * NYc);
  const int rem  = swz - bz * (NXc * NYc);
  const int by   = rem / NXc;
  const int bx   = rem - by * NXc;

  const int e   = bz;
  const int cnt = meta[e];
  if (by * 128 >= cnt) return;
  const int off = meta[32 + e];

  const int tid  = threadIdx.x;
  const int lane = tid & 63;
  const int wave = tid >> 6;
  const int wr   = wave >> 1, wc = wave & 1;
  const int n0   = bx * 128;

  // staging: chunk = 16 rows; lane l -> row l>>2, swizzled k-piece (r9 scheme)
  const int l4 = lane >> 2;
  const int kp = (((lane & 3) ^ ((lane >> 3) & 3))) * 8;   // shorts

  const u16* aptr[2];
  int aoff[2];
#pragma unroll
  for (int c = 0; c < 2; ++c) {
    int chunk = wave * 2 + c;
    int row = chunk * 16 + l4;
    int i = by * 128 + row;
    if (i >= cnt) i = cnt - 1;          // clamp tail (dup rows; epilogue guards)
    int srow = (MODE == 0) ? list[off + i] : (off + i);
    aptr[c] = Abase + (size_t)srow * K_ + kp;
    aoff[c] = chunk * 512;
  }
  const u16* bptr[2];
  int boff[2];
#pragma unroll
  for (int c = 0; c < 2; ++c) {
    int chunk = wave * 2 + c;
    int row = chunk * 16 + l4;
    bptr[c] = Bbase + ((size_t)e * N_ + n0 + row) * K_ + kp;
    boff[c] = chunk * 512;
  }

  f32x4 acc[4][4] = {};
  const int r16 = lane & 15;
  const int kqs = (((lane >> 4) ^ ((lane >> 1) & 3))) * 8; // swizzled read slot

  // buffer rotation pointers (kept in registers; no dynamic indexing)
  u16 *a0 = Al, *a1 = Al + ABUF, *a2 = Al + 2 * ABUF;
  u16 *b0 = Bl, *b1 = Bl + ABUF, *b2 = Bl + 2 * ABUF;

  // prologue: stage tile 0 -> buf0, tile 1 -> buf1 (8 loads in flight per wave)
#pragma unroll
  for (int c = 0; c < 2; ++c) { gload16(aptr[c], a0 + aoff[c]); gload16(bptr[c], b0 + boff[c]); }
#pragma unroll
  for (int c = 0; c < 2; ++c) { gload16(aptr[c] + 32, a1 + aoff[c]); gload16(bptr[c] + 32, b1 + boff[c]); }

  for (int t = 0; t < NT; ++t) {
    // wait ONLY this tile's 4 loads; next tile's stay in flight
    if (t + 1 < NT) asm volatile("s_waitcnt vmcnt(4)" ::: "memory");
    else            asm volatile("s_waitcnt vmcnt(0)" ::: "memory");
    __builtin_amdgcn_s_barrier();           // tile t visible to all waves

    if (t + 2 < NT) {                       // prefetch t+2 into the spare buffer
      int k0 = (t + 2) * 32;
#pragma unroll
      for (int c = 0; c < 2; ++c) { gload16(aptr[c] + k0, a2 + aoff[c]); gload16(bptr[c] + k0, b2 + boff[c]); }
    }

    bf16x8 af[4], bfv[4];
#pragma unroll
    for (int m = 0; m < 4; ++m)
      af[m] = *reinterpret_cast<const bf16x8*>(&a0[(wr*64 + m*16 + r16) * 32 + kqs]);
#pragma unroll
    for (int n = 0; n < 4; ++n)
      bfv[n] = *reinterpret_cast<const bf16x8*>(&b0[(wc*64 + n*16 + r16) * 32 + kqs]);
    __builtin_amdgcn_s_setprio(1);
#pragma unroll
    for (int m = 0; m < 4; ++m)
#pragma unroll
      for (int n = 0; n < 4; ++n)
        acc[m][n] = __builtin_amdgcn_mfma_f32_16x16x32_bf16(af[m], bfv[n], acc[m][n], 0, 0, 0);
    __builtin_amdgcn_s_setprio(0);

    u16* ta = a0; a0 = a1; a1 = a2; a2 = ta;   // rotate buffers
    u16* tb = b0; b0 = b1; b1 = b2; b2 = tb;
  }

  // epilogue: C/D frag layout col=lane&15, row=(lane>>4)*4+reg
  const int colb = n0 + wc * 64 + r16;
  const int rb4  = wr * 64 + ((lane >> 4) << 2);
#pragma unroll
  for (int m = 0; m < 4; ++m) {
#pragma unroll
    for (int r = 0; r < 4; ++r) {
      int i = by * 128 + rb4 + m * 16 + r;
      if (i >= cnt) continue;
      if (MODE == 0) {
        u16* hp = (u16*)Cout + (size_t)(off + i) * N_;
#pragma unroll
        for (int n = 0; n < 4; ++n) {
          float v = acc[m][n][r];
          v = v / (1.f + expf(-v));            // silu
          hp[colb + n * 16] = f2bf(v);
        }
      } else {
        int   tok = list[off + i];
        float w   = wgt[off + i];
        float* o = (float*)Cout + (size_t)tok * N_;
#pragma unroll
        for (int n = 0; n < 4; ++n)
          atomicAdd(&o[colb + n * 16], w * acc[m][n][r]);
      }
    }
  }
}

// ---------------- dense fallback (small-ws path) ----------------
__global__ __launch_bounds__(256) void combine_kernel(
    const float* __restrict__ logits, float* __restrict__ combine)
{
  int t = blockIdx.x * 256 + threadIdx.x;
  if (t >= Tt) return;
  float4 lo = *reinterpret_cast<const float4*>(logits + (size_t)t * 8);
  float4 hi = *reinterpret_cast<const float4*>(logits + (size_t)t * 8 + 4);
  float s[8] = {lo.x, lo.y, lo.z, lo.w, hi.x, hi.y, hi.z, hi.w};
  int i1 = 0; float m1 = s[0];
#pragma unroll
  for (int e = 1; e < 8; ++e) if (s[e] > m1) { m1 = s[e]; i1 = e; }
  int i2 = -1; float m2 = -__builtin_inff();
#pragma unroll
  for (int e = 0; e < 8; ++e) if (e != i1 && s[e] > m2) { m2 = s[e]; i2 = e; }
  float wa = 1.f / (1.f + expf(m2 - m1));
#pragma unroll
  for (int e = 0; e < 8; ++e)
    combine[(size_t)t * 8 + e] = (e == i1) ? wa : ((e == i2) ? (1.f - wa) : 0.f);
}

template<int MODE, int N_, int K_>
__global__ __launch_bounds__(256) void gemm_dense(
    const float* __restrict__ A, const float* __restrict__ Bg,
    float* __restrict__ C, const float* __restrict__ combine,
    int expert, int first)
{
  constexpr int BM = 128, BN = 128, BK = 32, LDT = 40;
  __shared__ u16 Al[BM * LDT];
  __shared__ u16 Bl[BN * LDT];
  const int tid  = threadIdx.x;
  const int lane = tid & 63;
  const int wave = tid >> 6;
  const int wr = wave >> 1, wc = wave & 1;
  const int m0 = blockIdx.y * BM;
  const int n0 = blockIdx.x * BN;
  f32x4 acc[4][4] = {};
  for (int k0 = 0; k0 < K_; k0 += BK) {
#pragma unroll
    for (int i = 0; i < 4; ++i) {
      int f = tid + 256 * i;
      int row = f >> 3;
      int c4 = (f & 7) << 2;
      float4 v = *reinterpret_cast<const float4*>(A + (size_t)(m0 + row) * K_ + k0 + c4);
      ushort4 b;
      b.x = f2bf(v.x); b.y = f2bf(v.y); b.z = f2bf(v.z); b.w = f2bf(v.w);
      *reinterpret_cast<ushort4*>(&Al[row * LDT + c4]) = b;
    }
    {
      int n  = tid & 127;
      int kb = (tid >> 7) << 4;
      const float* bp = Bg + (size_t)(k0 + kb) * N_ + n0 + n;
      u16 tmp[16];
#pragma unroll
      for (int kk = 0; kk < 16; ++kk)
        tmp[kk] = f2bf(bp[(size_t)kk * N_]);
      u16* p = &Bl[n * LDT + kb];
#pragma unroll
      for (int i = 0; i < 4; ++i) {
        ushort4 b;
        b.x = tmp[i*4+0]; b.y = tmp[i*4+1]; b.z = tmp[i*4+2]; b.w = tmp[i*4+3];
        *reinterpret_cast<ushort4*>(p + i * 4) = b;
      }
    }
    __syncthreads();
    bf16x8 af[4], bfr[4];
    const int kq  = (lane >> 4) << 3;
    const int r16 = lane & 15;
#pragma unroll
    for (int m = 0; m < 4; ++m)
      af[m] = *reinterpret_cast<const bf16x8*>(&Al[(wr*64 + m*16 + r16) * LDT + kq]);
#pragma unroll
    for (int n = 0; n < 4; ++n)
      bfr[n] = *reinterpret_cast<const bf16x8*>(&Bl[(wc*64 + n*16 + r16) * LDT + kq]);
#pragma unroll
    for (int m = 0; m < 4; ++m)
#pragma unroll
      for (int n = 0; n < 4; ++n)
        acc[m][n] = __builtin_amdgcn_mfma_f32_16x16x32_bf16(af[m], bfr[n], acc[m][n], 0, 0, 0);
    __syncthreads();
  }
  const int col0 = n0 + wc * 64 + (lane & 15);
  const int rbs  = m0 + wr * 64 + ((lane >> 4) << 2);
#pragma unroll
  for (int m = 0; m < 4; ++m) {
#pragma unroll
    for (int r = 0; r < 4; ++r) {
      int row = rbs + m * 16 + r;
      if (MODE == 0) {
#pragma unroll
        for (int n = 0; n < 4; ++n) {
          float v = acc[m][n][r];
          v = v / (1.f + expf(-v));
          C[(size_t)row * N_ + col0 + n * 16] = v;
        }
      } else {
        float w = combine[(size_t)row * Ee + expert];
        if (first) {
#pragma unroll
          for (int n = 0; n < 4; ++n)
            C[(size_t)row * N_ + col0 + n * 16] = w * acc[m][n][r];
        } else {
#pragma unroll
          for (int n = 0; n < 4; ++n)
            C[(size_t)row * N_ + col0 + n * 16] += w * acc[m][n][r];
        }
      }
    }
  }
}

extern "C" void kernel_launch(void* const* d_in, const int* in_sizes, int n_in,
                              void* d_out, int out_size, void* d_ws, size_t ws_size,
                              hipStream_t stream)
{
  const float* x  = (const float*)d_in[0];   // [2,2048,1024]
  const float* gw = (const float*)d_in[1];   // [8,1024]
  const float* w1 = (const float*)d_in[2];   // [8,1024,2048]
  const float* w2 = (const float*)d_in[3];   // [8,2048,1024]
  float* out    = (float*)d_out;
  float* logits = out + (size_t)Tt * Dd;

  int*   meta = (int*)d_ws;                       // 64 ints
  int*   list = (int*)((char*)d_ws + 256);        // 8192 ints
  float* wgt  = (float*)((char*)d_ws + 256 + 32768);
  u16*   xb   = (u16*)((char*)d_ws + 262144);                         // 8 MB
  u16*   h1   = (u16*)((char*)d_ws + 262144 + 8388608);               // 32 MB
  u16*   wT   = (u16*)((char*)d_ws + 262144 + 8388608 + 33554432);    // 33.5 MB
  const size_t NEED = 262144ull + 8388608ull + 33554432ull + 33554432ull;

  if (ws_size >= NEED) {
    router_kernel<<<Tt / 4, 256, 0, stream>>>(x, gw, logits, xb);
    hipMemsetAsync(out, 0, (size_t)Tt * Dd * sizeof(float), stream);
    build_kernel<<<1, 256, 0, stream>>>(logits, meta, list, wgt);
    transpose_bf16_kernel<<<dim3(Ff/64, Dd/64, Ee), 256, 0, stream>>>(w1, wT, Dd, Ff);
    gemm_g<0, Ff, Dd><<<dim3(Ff/128, 32, 8), 256, 0, stream>>>(xb, wT, h1, meta, list, wgt);
    transpose_bf16_kernel<<<dim3(Dd/64, Ff/64, Ee), 256, 0, stream>>>(w2, wT, Ff, Dd);
    gemm_g<1, Dd, Ff><<<dim3(Dd/128, 32, 8), 256, 0, stream>>>(h1, wT, out, meta, list, wgt);
  } else {
    float* combine = (float*)d_ws;
    float* h1d     = combine + (size_t)Tt * Ee;
    router_kernel<<<Tt / 4, 256, 0, stream>>>(x, gw, logits, nullptr);
    combine_kernel<<<Tt / 256, 256, 0, stream>>>(logits, combine);
    size_t cb = (size_t)Tt * Ee * sizeof(float);
    size_t avail = ws_size > cb ? (ws_size - cb) : 0;
    long maxrows = (long)(avail / ((size_t)Ff * sizeof(float)));
    int chunk = (maxrows >= Tt) ? Tt : (int)((maxrows / 128) * 128);
    if (chunk < 128) chunk = 128;
    for (int c0 = 0; c0 < Tt; c0 += chunk) {
      int rows = (Tt - c0) < chunk ? (Tt - c0) : chunk;
      for (int e = 0; e < Ee; ++e) {
        gemm_dense<0, Ff, Dd><<<dim3(Ff/128, rows/128), 256, 0, stream>>>(
            x + (size_t)c0 * Dd, w1 + (size_t)e * Dd * Ff, h1d, nullptr, e, 0);
        gemm_dense<1, Dd, Ff><<<dim3(Dd/128, rows/128), 256, 0, stream>>>(
            h1d, w2 + (size_t)e * Ff * Dd, out + (size_t)c0 * Dd,
            combine + (size_t)c0 * Ee, e, (e == 0) ? 1 : 0);
      }
    }
  }
}